// Round 3
// baseline (264.266 us; speedup 1.0000x reference)
//
#include <hip/hip_runtime.h>
#include <limits.h>

#define TABLE_BITS 21
#define TABLE_SIZE (1u << TABLE_BITS)      // 2,097,152 entries > max key 1,999,999
#define TABLE_MASK (TABLE_SIZE - 1u)
#define BLOCK 256
#define EPT 4                              // elements per thread
#define CHUNK (BLOCK * EPT)                // 1024 elements per block
#define RANK_BIT 0x40000000
#define RANK_MASK 0x3FFFFFFF
#define NXCD 8

__device__ __forceinline__ unsigned xcc_id() {
    unsigned x;
    asm volatile("s_getreg_b32 %0, hwreg(HW_REG_XCC_ID)" : "=s"(x));
    return x & (NXCD - 1);
}

// Raw L2-side atomic min: no sc0/sc1 bits -> should execute in the issuing
// XCD's TCC (write-back cached) instead of memory-side. Only correct here
// because each XCD owns a private table slice (merged afterwards).
__device__ __forceinline__ void atomic_smin_l2(int* p, int v) {
    asm volatile("global_atomic_smin %0, %1, off"
                 :: "v"((unsigned long long)(uintptr_t)p), "v"(v) : "memory");
}

// Monotone-safe conditional atomic: a stale cached read can only be HIGHER
// than the true current value (values monotonically decrease), so skipping
// when (seen <= i) is always safe; staleness only costs a redundant atomic.
__device__ __forceinline__ void cond_min(int* __restrict__ tbl, unsigned key, int i) {
    int seen = tbl[key];
    if (i < seen) atomic_smin_l2(&tbl[key], i);
}

// ---------- K1: per-XCD first-occurrence, filtered + L2-local atomics ----------
__global__ __launch_bounds__(BLOCK) void k_first_idx_local(const int* __restrict__ x, int n,
                                                           int* __restrict__ tables) {
    int* tbl = tables + (size_t)xcc_id() * TABLE_SIZE;
    int base = (blockIdx.x * BLOCK + threadIdx.x) * EPT;
    if (base + EPT <= n) {
        int4 v = *reinterpret_cast<const int4*>(x + base);
        cond_min(tbl, (unsigned)v.x & TABLE_MASK, base);
        cond_min(tbl, (unsigned)v.y & TABLE_MASK, base + 1);
        cond_min(tbl, (unsigned)v.z & TABLE_MASK, base + 2);
        cond_min(tbl, (unsigned)v.w & TABLE_MASK, base + 3);
    } else {
        for (int i = base; i < n; ++i)
            cond_min(tbl, (unsigned)x[i] & TABLE_MASK, i);
    }
}

// K1b: merge the 8 per-XCD tables into the canonical table (element-wise min).
__global__ __launch_bounds__(BLOCK) void k_merge(const int* __restrict__ tables,
                                                 int* __restrict__ table) {
    int idx = (blockIdx.x * BLOCK + threadIdx.x) * 4;
    int4 m = *reinterpret_cast<const int4*>(tables + idx);
    #pragma unroll
    for (int k = 1; k < NXCD; ++k) {
        int4 t = *reinterpret_cast<const int4*>(tables + (size_t)k * TABLE_SIZE + idx);
        m.x = min(m.x, t.x); m.y = min(m.y, t.y);
        m.z = min(m.z, t.z); m.w = min(m.w, t.w);
    }
    *reinterpret_cast<int4*>(table + idx) = m;
}

// ---------- K2: count first-occurrence flags + publish packed bitmask ----------
__global__ __launch_bounds__(BLOCK) void k_count(const int* __restrict__ x, int n,
                                                 const int* __restrict__ table,
                                                 int* __restrict__ blockSums,
                                                 unsigned long long* __restrict__ bitmask) {
    int tid = threadIdx.x;
    int lane = tid & 63, w = tid >> 6;
    int base = blockIdx.x * CHUNK + tid * EPT;
    int flags[EPT];
    if (base + EPT <= n) {
        int4 v = *reinterpret_cast<const int4*>(x + base);
        flags[0] = (table[(unsigned)v.x & TABLE_MASK] == base);
        flags[1] = (table[(unsigned)v.y & TABLE_MASK] == base + 1);
        flags[2] = (table[(unsigned)v.z & TABLE_MASK] == base + 2);
        flags[3] = (table[(unsigned)v.w & TABLE_MASK] == base + 3);
    } else {
        #pragma unroll
        for (int j = 0; j < EPT; ++j) {
            flags[j] = 0;
            if (base + j < n)
                flags[j] = (table[(unsigned)x[base + j] & TABLE_MASK] == base + j);
        }
    }
    int cnt = 0;
    #pragma unroll
    for (int j = 0; j < EPT; ++j) {
        unsigned long long mj = __ballot(flags[j]);
        if (lane == 0) bitmask[((size_t)blockIdx.x * (BLOCK / 64) + w) * EPT + j] = mj;
        cnt += flags[j];
    }
    for (int off = 32; off > 0; off >>= 1)
        cnt += __shfl_down(cnt, off, 64);
    __shared__ int ws[BLOCK / 64];
    if (lane == 0) ws[w] = cnt;
    __syncthreads();
    if (tid == 0) {
        int s = 0;
        #pragma unroll
        for (int q = 0; q < BLOCK / 64; ++q) s += ws[q];
        blockSums[blockIdx.x] = s;
    }
}

// ---------- K3: single-block exclusive scan of blockSums ----------
__global__ __launch_bounds__(BLOCK) void k_scan(int* __restrict__ sums, int B) {
    __shared__ int lds[BLOCK];
    int tid = threadIdx.x;
    int carry = 0;
    for (int base = 0; base < B; base += BLOCK) {
        int idx = base + tid;
        int v = (idx < B) ? sums[idx] : 0;
        lds[tid] = v;
        __syncthreads();
        for (int off = 1; off < BLOCK; off <<= 1) {
            int t = (tid >= off) ? lds[tid - off] : 0;
            __syncthreads();
            lds[tid] += t;
            __syncthreads();
        }
        if (idx < B) sums[idx] = carry + lds[tid] - v;   // exclusive
        carry += lds[BLOCK - 1];
        __syncthreads();
    }
}

// ---------- K4: assign ranks using the bitmask (no table gathers) ----------
__global__ __launch_bounds__(BLOCK) void k_rank(const int* __restrict__ x, int n,
                                                int* __restrict__ table,
                                                const int* __restrict__ blockSums,
                                                const unsigned long long* __restrict__ bitmask) {
    int tid = threadIdx.x;
    int lane = tid & 63, w = tid >> 6;
    int base = blockIdx.x * CHUNK + tid * EPT;
    const unsigned long long* bm = bitmask + ((size_t)blockIdx.x * (BLOCK / 64) + w) * EPT;
    int flags[EPT];
    int cnt = 0;
    #pragma unroll
    for (int j = 0; j < EPT; ++j) {
        flags[j] = (int)((bm[j] >> lane) & 1ull);
        cnt += flags[j];
    }
    __shared__ int lds[BLOCK];
    lds[tid] = cnt;
    __syncthreads();
    for (int off = 1; off < BLOCK; off <<= 1) {
        int t = (tid >= off) ? lds[tid - off] : 0;
        __syncthreads();
        lds[tid] += t;
        __syncthreads();
    }
    int r = blockSums[blockIdx.x] + lds[tid] - cnt;
    if (cnt) {
        if (base + EPT <= n) {
            int4 v = *reinterpret_cast<const int4*>(x + base);
            if (flags[0]) table[(unsigned)v.x & TABLE_MASK] = (r++) | RANK_BIT;
            if (flags[1]) table[(unsigned)v.y & TABLE_MASK] = (r++) | RANK_BIT;
            if (flags[2]) table[(unsigned)v.z & TABLE_MASK] = (r++) | RANK_BIT;
            if (flags[3]) table[(unsigned)v.w & TABLE_MASK] = (r++) | RANK_BIT;
        } else {
            #pragma unroll
            for (int j = 0; j < EPT; ++j)
                if (flags[j]) table[(unsigned)x[base + j] & TABLE_MASK] = (r++) | RANK_BIT;
        }
    }
}

// ---------- K5: gather rank, apply max_tokens cutoff, write output ----------
__global__ __launch_bounds__(BLOCK) void k_out(const int* __restrict__ x, int n,
                                               const int* __restrict__ table,
                                               const int* __restrict__ mtp,
                                               int* __restrict__ out) {
    int mt = mtp[0];
    int base = (blockIdx.x * BLOCK + threadIdx.x) * EPT;
    if (base + EPT <= n) {
        int4 v = *reinterpret_cast<const int4*>(x + base);
        int4 o;
        int r;
        r = table[(unsigned)v.x & TABLE_MASK] & RANK_MASK; o.x = (r < mt) ? r + 1 : 0;
        r = table[(unsigned)v.y & TABLE_MASK] & RANK_MASK; o.y = (r < mt) ? r + 1 : 0;
        r = table[(unsigned)v.z & TABLE_MASK] & RANK_MASK; o.z = (r < mt) ? r + 1 : 0;
        r = table[(unsigned)v.w & TABLE_MASK] & RANK_MASK; o.w = (r < mt) ? r + 1 : 0;
        *reinterpret_cast<int4*>(out + base) = o;
    } else {
        for (int i = base; i < n; ++i) {
            int r = table[(unsigned)x[i] & TABLE_MASK] & RANK_MASK;
            out[i] = (r < mt) ? r + 1 : 0;
        }
    }
}

extern "C" void kernel_launch(void* const* d_in, const int* in_sizes, int n_in,
                              void* d_out, int out_size, void* d_ws, size_t ws_size,
                              hipStream_t stream) {
    const int* x   = (const int*)d_in[0];
    const int* mtp = (const int*)d_in[1];
    int n = in_sizes[0];
    int* out = (int*)d_out;

    const size_t tbytes = (size_t)TABLE_SIZE * sizeof(int);

    int* table  = (int*)d_ws;                          // 8 MB canonical table
    int* tables = table + TABLE_SIZE;                  // 8 x 8 MB per-XCD
    char* extra = (char*)d_ws + tbytes * (1 + NXCD);
    int* blockSums = (int*)extra;                      // 64 KB region
    unsigned long long* bitmask = (unsigned long long*)(extra + 65536);

    int B = (n + CHUNK - 1) / CHUNK;

    hipMemsetAsync(tables, 0x7F, tbytes * NXCD, stream);   // "infinity" in all 8
    k_first_idx_local<<<(n + CHUNK - 1) / CHUNK, BLOCK, 0, stream>>>(x, n, tables);
    k_merge<<<TABLE_SIZE / (BLOCK * 4), BLOCK, 0, stream>>>(tables, table);
    k_count<<<B, BLOCK, 0, stream>>>(x, n, table, blockSums, bitmask);
    k_scan <<<1, BLOCK, 0, stream>>>(blockSums, B);
    k_rank <<<B, BLOCK, 0, stream>>>(x, n, table, blockSums, bitmask);
    k_out  <<<(n + CHUNK - 1) / CHUNK, BLOCK, 0, stream>>>(x, n, table, mtp, out);
}

// Round 4
// 160.365 us; speedup vs baseline: 1.6479x; 1.6479x over previous
//
#include <hip/hip_runtime.h>
#include <stdint.h>

#define TABLE_BITS 21
#define TABLE_SIZE (1u << TABLE_BITS)      // 2,097,152 entries > max key 1,999,999
#define TABLE_MASK (TABLE_SIZE - 1u)
#define BLOCK 256
#define EPT 4
#define CHUNK (BLOCK * EPT)                // 1024 elements per block
#define RANK_BIT 0x40000000
#define RANK_MASK 0x3FFFFFFF
#define NB 256                             // key-range buckets
#define BSHIFT (TABLE_BITS - 8)            // 13 -> 8192 keys per bucket
#define KPB (1 << BSHIFT)
#define KLOW_MASK (KPB - 1)
#define INF_PAT 0x7f7f7f7f

// ---- block exclusive scan (NT threads, NT/64 waves, NT/64 <= 64) ----
template<int NT>
__device__ __forceinline__ int blk_excl_scan(int v, int tid, int* total) {
    constexpr int NW = NT / 64;
    int lane = tid & 63, w = tid >> 6;
    int inc = v;
    #pragma unroll
    for (int off = 1; off < 64; off <<= 1) {
        int u = __shfl_up(inc, off, 64);
        if (lane >= off) inc += u;
    }
    __shared__ int part[NW];
    if (lane == 63) part[w] = inc;
    __syncthreads();
    if (tid < NW) {
        int p = part[tid];
        #pragma unroll
        for (int off = 1; off < NW; off <<= 1) {
            int u = __shfl_up(p, off, 64);
            if (tid >= off) p += u;
        }
        part[tid] = p;
    }
    __syncthreads();
    int excl = ((w == 0) ? 0 : part[w - 1]) + inc - v;
    int tot = part[NW - 1];
    __syncthreads();                        // part[] reusable by caller's next iter
    if (total) *total = tot;
    return excl;
}

// ---------- A: per-block 256-bucket histogram (LDS atomics only) ----------
__global__ __launch_bounds__(BLOCK) void k_hist(const int* __restrict__ x, int n,
                                                unsigned* __restrict__ hist) {
    __shared__ unsigned cnt[NB];
    int tid = threadIdx.x;
    cnt[tid] = 0;                           // BLOCK == NB
    __syncthreads();
    int base = blockIdx.x * CHUNK + tid * EPT;
    if (base + EPT <= n) {
        int4 v = *reinterpret_cast<const int4*>(x + base);
        atomicAdd(&cnt[((unsigned)v.x & TABLE_MASK) >> BSHIFT], 1u);
        atomicAdd(&cnt[((unsigned)v.y & TABLE_MASK) >> BSHIFT], 1u);
        atomicAdd(&cnt[((unsigned)v.z & TABLE_MASK) >> BSHIFT], 1u);
        atomicAdd(&cnt[((unsigned)v.w & TABLE_MASK) >> BSHIFT], 1u);
    } else {
        for (int i = base; i < n; ++i)
            atomicAdd(&cnt[((unsigned)x[i] & TABLE_MASK) >> BSHIFT], 1u);
    }
    __syncthreads();
    hist[(size_t)blockIdx.x * NB + tid] = cnt[tid];
}

// ---------- B: per-bucket exclusive scan over blocks (in place) ----------
__global__ __launch_bounds__(256) void k_colscan(unsigned* __restrict__ hist, int SB,
                                                 unsigned* __restrict__ bucketTot) {
    int j = blockIdx.x, tid = threadIdx.x;
    unsigned carry = 0;
    for (int b0 = 0; b0 < SB; b0 += 256) {
        int b = b0 + tid;
        int v = (b < SB) ? (int)hist[(size_t)b * NB + j] : 0;
        int tot;
        int excl = blk_excl_scan<256>(v, tid, &tot);
        if (b < SB) hist[(size_t)b * NB + j] = carry + (unsigned)excl;
        carry += (unsigned)tot;
    }
    if (tid == 0) bucketTot[j] = carry;
}

// ---------- B2: exclusive scan of bucket totals -> bucket bases ----------
__global__ __launch_bounds__(256) void k_bucketbase(const unsigned* __restrict__ bucketTot,
                                                    unsigned* __restrict__ bucketBase) {
    int tid = threadIdx.x;
    int v = (int)bucketTot[tid];
    int tot;
    int excl = blk_excl_scan<256>(v, tid, &tot);
    bucketBase[tid] = (unsigned)excl;
    if (tid == 255) bucketBase[256] = (unsigned)(excl + v);
}

// ---------- C: scatter (key_low, pos) pairs into buckets (LDS offsets) ----------
__global__ __launch_bounds__(BLOCK) void k_scatter(const int* __restrict__ x, int n,
                                                   const unsigned* __restrict__ hist,
                                                   const unsigned* __restrict__ bucketBase,
                                                   unsigned long long* __restrict__ pairs) {
    __shared__ unsigned lcnt[NB];
    __shared__ unsigned sbase[NB];
    int tid = threadIdx.x;
    lcnt[tid] = 0;
    sbase[tid] = bucketBase[tid] + hist[(size_t)blockIdx.x * NB + tid];
    __syncthreads();
    int base = blockIdx.x * CHUNK + tid * EPT;
    unsigned bj[EPT], kl[EPT], lo[EPT];
    int nv = 0;
    if (base + EPT <= n) {
        int4 v = *reinterpret_cast<const int4*>(x + base);
        unsigned k0 = (unsigned)v.x & TABLE_MASK, k1 = (unsigned)v.y & TABLE_MASK;
        unsigned k2 = (unsigned)v.z & TABLE_MASK, k3 = (unsigned)v.w & TABLE_MASK;
        bj[0] = k0 >> BSHIFT; kl[0] = k0 & KLOW_MASK;
        bj[1] = k1 >> BSHIFT; kl[1] = k1 & KLOW_MASK;
        bj[2] = k2 >> BSHIFT; kl[2] = k2 & KLOW_MASK;
        bj[3] = k3 >> BSHIFT; kl[3] = k3 & KLOW_MASK;
        #pragma unroll
        for (int j = 0; j < EPT; ++j) lo[j] = atomicAdd(&lcnt[bj[j]], 1u);
        nv = EPT;
    } else {
        for (int i = base; i < n; ++i) {
            unsigned k = (unsigned)x[i] & TABLE_MASK;
            bj[nv] = k >> BSHIFT; kl[nv] = k & KLOW_MASK;
            lo[nv] = atomicAdd(&lcnt[bj[nv]], 1u);
            ++nv;
        }
    }
    __syncthreads();
    #pragma unroll
    for (int j = 0; j < EPT; ++j) {
        if (j < nv) {
            unsigned dst = sbase[bj[j]] + lo[j];
            pairs[dst] = ((unsigned long long)kl[j] << 32) | (unsigned)(base + j);
        }
    }
}

// ---------- D: per-bucket first-idx via LDS atomicMin; coalesced table write ----------
__global__ __launch_bounds__(512) void k_bucket_min(const unsigned long long* __restrict__ pairs,
                                                    const unsigned* __restrict__ bucketBase,
                                                    int* __restrict__ table) {
    __shared__ int fi[KPB];                 // 32 KB
    int j = blockIdx.x, tid = threadIdx.x;
    for (int k = tid; k < KPB; k += 512) fi[k] = INF_PAT;
    __syncthreads();
    unsigned s = bucketBase[j], e = bucketBase[j + 1];
    for (unsigned idx = s + tid; idx < e; idx += 512) {
        unsigned long long p = pairs[idx];
        atomicMin(&fi[(unsigned)(p >> 32)], (int)(unsigned)p);
    }
    __syncthreads();
    int* dst = table + (size_t)j * KPB;
    for (int k = tid; k < KPB; k += 512) dst[k] = fi[k];
}

// ---------- fallback: device-scope atomicMin into single table ----------
__global__ __launch_bounds__(BLOCK) void k_first_idx(const int* __restrict__ x, int n,
                                                     int* __restrict__ table) {
    int base = (blockIdx.x * BLOCK + threadIdx.x) * EPT;
    if (base + EPT <= n) {
        int4 v = *reinterpret_cast<const int4*>(x + base);
        atomicMin(&table[(unsigned)v.x & TABLE_MASK], base);
        atomicMin(&table[(unsigned)v.y & TABLE_MASK], base + 1);
        atomicMin(&table[(unsigned)v.z & TABLE_MASK], base + 2);
        atomicMin(&table[(unsigned)v.w & TABLE_MASK], base + 3);
    } else {
        for (int i = base; i < n; ++i)
            atomicMin(&table[(unsigned)x[i] & TABLE_MASK], i);
    }
}

// ---------- K2: count first-occurrence flags + publish packed bitmask ----------
__global__ __launch_bounds__(BLOCK) void k_count(const int* __restrict__ x, int n,
                                                 const int* __restrict__ table,
                                                 int* __restrict__ blockSums,
                                                 unsigned long long* __restrict__ bitmask) {
    int tid = threadIdx.x;
    int lane = tid & 63, w = tid >> 6;
    int base = blockIdx.x * CHUNK + tid * EPT;
    int flags[EPT];
    if (base + EPT <= n) {
        int4 v = *reinterpret_cast<const int4*>(x + base);
        flags[0] = (table[(unsigned)v.x & TABLE_MASK] == base);
        flags[1] = (table[(unsigned)v.y & TABLE_MASK] == base + 1);
        flags[2] = (table[(unsigned)v.z & TABLE_MASK] == base + 2);
        flags[3] = (table[(unsigned)v.w & TABLE_MASK] == base + 3);
    } else {
        #pragma unroll
        for (int j = 0; j < EPT; ++j) {
            flags[j] = 0;
            if (base + j < n)
                flags[j] = (table[(unsigned)x[base + j] & TABLE_MASK] == base + j);
        }
    }
    int cnt = 0;
    #pragma unroll
    for (int j = 0; j < EPT; ++j) {
        unsigned long long mj = __ballot(flags[j]);
        if (lane == 0) bitmask[((size_t)blockIdx.x * (BLOCK / 64) + w) * EPT + j] = mj;
        cnt += flags[j];
    }
    for (int off = 32; off > 0; off >>= 1)
        cnt += __shfl_down(cnt, off, 64);
    __shared__ int ws[BLOCK / 64];
    if (lane == 0) ws[w] = cnt;
    __syncthreads();
    if (tid == 0) {
        int s = 0;
        #pragma unroll
        for (int q = 0; q < BLOCK / 64; ++q) s += ws[q];
        blockSums[blockIdx.x] = s;
    }
}

// ---------- K3: fast single-block scan of blockSums ----------
__global__ __launch_bounds__(1024) void k_scan(int* __restrict__ sums, int B) {
    int tid = threadIdx.x;
    int carry = 0;
    for (int b0 = 0; b0 < B; b0 += 1024) {
        int b = b0 + tid;
        int v = (b < B) ? sums[b] : 0;
        int tot;
        int excl = blk_excl_scan<1024>(v, tid, &tot);
        if (b < B) sums[b] = carry + excl;
        carry += tot;
    }
}

// ---------- K4: assign ranks using the bitmask ----------
__global__ __launch_bounds__(BLOCK) void k_rank(const int* __restrict__ x, int n,
                                                int* __restrict__ table,
                                                const int* __restrict__ blockSums,
                                                const unsigned long long* __restrict__ bitmask) {
    int tid = threadIdx.x;
    int lane = tid & 63, w = tid >> 6;
    int base = blockIdx.x * CHUNK + tid * EPT;
    const unsigned long long* bm = bitmask + ((size_t)blockIdx.x * (BLOCK / 64) + w) * EPT;
    int flags[EPT];
    int cnt = 0;
    #pragma unroll
    for (int j = 0; j < EPT; ++j) {
        flags[j] = (int)((bm[j] >> lane) & 1ull);
        cnt += flags[j];
    }
    __shared__ int lds[BLOCK];
    lds[tid] = cnt;
    __syncthreads();
    for (int off = 1; off < BLOCK; off <<= 1) {
        int t = (tid >= off) ? lds[tid - off] : 0;
        __syncthreads();
        lds[tid] += t;
        __syncthreads();
    }
    int r = blockSums[blockIdx.x] + lds[tid] - cnt;
    if (cnt) {
        if (base + EPT <= n) {
            int4 v = *reinterpret_cast<const int4*>(x + base);
            if (flags[0]) table[(unsigned)v.x & TABLE_MASK] = (r++) | RANK_BIT;
            if (flags[1]) table[(unsigned)v.y & TABLE_MASK] = (r++) | RANK_BIT;
            if (flags[2]) table[(unsigned)v.z & TABLE_MASK] = (r++) | RANK_BIT;
            if (flags[3]) table[(unsigned)v.w & TABLE_MASK] = (r++) | RANK_BIT;
        } else {
            #pragma unroll
            for (int j = 0; j < EPT; ++j)
                if (flags[j]) table[(unsigned)x[base + j] & TABLE_MASK] = (r++) | RANK_BIT;
        }
    }
}

// ---------- K5: gather rank, apply max_tokens cutoff ----------
__global__ __launch_bounds__(BLOCK) void k_out(const int* __restrict__ x, int n,
                                               const int* __restrict__ table,
                                               const int* __restrict__ mtp,
                                               int* __restrict__ out) {
    int mt = mtp[0];
    int base = (blockIdx.x * BLOCK + threadIdx.x) * EPT;
    if (base + EPT <= n) {
        int4 v = *reinterpret_cast<const int4*>(x + base);
        int4 o;
        int r;
        r = table[(unsigned)v.x & TABLE_MASK] & RANK_MASK; o.x = (r < mt) ? r + 1 : 0;
        r = table[(unsigned)v.y & TABLE_MASK] & RANK_MASK; o.y = (r < mt) ? r + 1 : 0;
        r = table[(unsigned)v.z & TABLE_MASK] & RANK_MASK; o.z = (r < mt) ? r + 1 : 0;
        r = table[(unsigned)v.w & TABLE_MASK] & RANK_MASK; o.w = (r < mt) ? r + 1 : 0;
        *reinterpret_cast<int4*>(out + base) = o;
    } else {
        for (int i = base; i < n; ++i) {
            int r = table[(unsigned)x[i] & TABLE_MASK] & RANK_MASK;
            out[i] = (r < mt) ? r + 1 : 0;
        }
    }
}

extern "C" void kernel_launch(void* const* d_in, const int* in_sizes, int n_in,
                              void* d_out, int out_size, void* d_ws, size_t ws_size,
                              hipStream_t stream) {
    const int* x   = (const int*)d_in[0];
    const int* mtp = (const int*)d_in[1];
    int n = in_sizes[0];
    int* out = (int*)d_out;

    int SB = (n + CHUNK - 1) / CHUNK;      // blocks over the data

    // workspace layout
    auto align16 = [](size_t v) { return (v + 15) & ~(size_t)15; };
    size_t off = 0;
    int* table = (int*)d_ws;                                   off = align16(off + (size_t)TABLE_SIZE * 4);
    unsigned long long* pairs = (unsigned long long*)((char*)d_ws + off); off = align16(off + (size_t)n * 8);
    unsigned* hist = (unsigned*)((char*)d_ws + off);           off = align16(off + (size_t)SB * NB * 4);
    unsigned* bucketTot = (unsigned*)((char*)d_ws + off);      off = align16(off + (size_t)NB * 4);
    unsigned* bucketBase = (unsigned*)((char*)d_ws + off);     off = align16(off + (size_t)(NB + 1) * 4);
    int* blockSums = (int*)((char*)d_ws + off);                off = align16(off + (size_t)SB * 4);
    unsigned long long* bitmask = (unsigned long long*)((char*)d_ws + off);
    off = align16(off + (size_t)SB * (BLOCK / 64) * EPT * 8);

    if (ws_size >= off) {
        // bucketed, global-atomic-free first-idx build (also replaces memset)
        k_hist      <<<SB, BLOCK, 0, stream>>>(x, n, hist);
        k_colscan   <<<NB, 256,   0, stream>>>(hist, SB, bucketTot);
        k_bucketbase<<<1,  256,   0, stream>>>(bucketTot, bucketBase);
        k_scatter   <<<SB, BLOCK, 0, stream>>>(x, n, hist, bucketBase, pairs);
        k_bucket_min<<<NB, 512,   0, stream>>>(pairs, bucketBase, table);
    } else {
        hipMemsetAsync(table, 0x7F, (size_t)TABLE_SIZE * 4, stream);
        k_first_idx<<<SB, BLOCK, 0, stream>>>(x, n, table);
    }
    k_count<<<SB, BLOCK, 0, stream>>>(x, n, table, blockSums, bitmask);
    k_scan <<<1, 1024, 0, stream>>>(blockSums, SB);
    k_rank <<<SB, BLOCK, 0, stream>>>(x, n, table, blockSums, bitmask);
    k_out  <<<SB, BLOCK, 0, stream>>>(x, n, table, mtp, out);
}

// Round 5
// 128.701 us; speedup vs baseline: 2.0533x; 1.2460x over previous
//
#include <hip/hip_runtime.h>
#include <stdint.h>

#define TABLE_BITS 21
#define TABLE_SIZE (1u << TABLE_BITS)      // 2,097,152 entries > max key 1,999,999
#define TABLE_MASK (TABLE_SIZE - 1u)
#define BLOCK 256
#define EPT 4
#define CHUNK (BLOCK * EPT)                // 1024 elements/block (flags/rank/out)
#define EPT2 16
#define CHUNK2 (BLOCK * EPT2)              // 4096 elements/block (hist/scatter)
#define RANK_BIT 0x40000000
#define RANK_MASK 0x3FFFFFFF
#define NB 256                             // key-range buckets
#define BSHIFT (TABLE_BITS - 8)            // 8192 keys per bucket
#define KPB (1 << BSHIFT)
#define KLOW_MASK (KPB - 1)
#define INF_PAT 0x7f7f7f7f
#define BJ_INVALID 0xFFFFFFFFu

// ---- block exclusive scan (NT threads) ----
template<int NT>
__device__ __forceinline__ int blk_excl_scan(int v, int tid, int* total) {
    constexpr int NW = NT / 64;
    int lane = tid & 63, w = tid >> 6;
    int inc = v;
    #pragma unroll
    for (int off = 1; off < 64; off <<= 1) {
        int u = __shfl_up(inc, off, 64);
        if (lane >= off) inc += u;
    }
    __shared__ int part[NW];
    if (lane == 63) part[w] = inc;
    __syncthreads();
    if (tid < NW) {
        int p = part[tid];
        #pragma unroll
        for (int off = 1; off < NW; off <<= 1) {
            int u = __shfl_up(p, off, 64);
            if (tid >= off) p += u;
        }
        part[tid] = p;
    }
    __syncthreads();
    int excl = ((w == 0) ? 0 : part[w - 1]) + inc - v;
    int tot = part[NW - 1];
    __syncthreads();
    if (total) *total = tot;
    return excl;
}

// ---------- A: per-block 256-bucket histogram, EPT2=16 coalesced ----------
__global__ __launch_bounds__(BLOCK) void k_hist(const int* __restrict__ x, int n,
                                                unsigned* __restrict__ hist) {
    __shared__ unsigned cnt[NB];
    int tid = threadIdx.x;
    cnt[tid] = 0;
    __syncthreads();
    int e0 = blockIdx.x * CHUNK2;
    #pragma unroll
    for (int k = 0; k < EPT2 / 4; ++k) {
        int idx = e0 + k * (BLOCK * 4) + tid * 4;
        if (idx + 4 <= n) {
            int4 v = *reinterpret_cast<const int4*>(x + idx);
            atomicAdd(&cnt[((unsigned)v.x & TABLE_MASK) >> BSHIFT], 1u);
            atomicAdd(&cnt[((unsigned)v.y & TABLE_MASK) >> BSHIFT], 1u);
            atomicAdd(&cnt[((unsigned)v.z & TABLE_MASK) >> BSHIFT], 1u);
            atomicAdd(&cnt[((unsigned)v.w & TABLE_MASK) >> BSHIFT], 1u);
        } else {
            for (int i = idx; i < n; ++i)
                atomicAdd(&cnt[((unsigned)x[i] & TABLE_MASK) >> BSHIFT], 1u);
        }
    }
    __syncthreads();
    hist[(size_t)blockIdx.x * NB + tid] = cnt[tid];
}

// ---------- B: per-bucket exclusive scan over blocks (in place) ----------
__global__ __launch_bounds__(256) void k_colscan(unsigned* __restrict__ hist, int SB2,
                                                 unsigned* __restrict__ bucketTot) {
    int j = blockIdx.x, tid = threadIdx.x;
    unsigned carry = 0;
    for (int b0 = 0; b0 < SB2; b0 += 256) {
        int b = b0 + tid;
        int v = (b < SB2) ? (int)hist[(size_t)b * NB + j] : 0;
        int tot;
        int excl = blk_excl_scan<256>(v, tid, &tot);
        if (b < SB2) hist[(size_t)b * NB + j] = carry + (unsigned)excl;
        carry += (unsigned)tot;
    }
    if (tid == 0) bucketTot[j] = carry;
}

// ---------- B2: exclusive scan of bucket totals ----------
__global__ __launch_bounds__(256) void k_bucketbase(const unsigned* __restrict__ bucketTot,
                                                    unsigned* __restrict__ bucketBase) {
    int tid = threadIdx.x;
    int v = (int)bucketTot[tid];
    int tot;
    int excl = blk_excl_scan<256>(v, tid, &tot);
    bucketBase[tid] = (unsigned)excl;
    if (tid == 255) bucketBase[256] = (unsigned)(excl + v);
}

// ---------- C: LDS-staged scatter -> pairs grouped by bucket, burst writes ----------
__global__ __launch_bounds__(BLOCK) void k_scatter(const int* __restrict__ x, int n,
                                                   const unsigned* __restrict__ hist,
                                                   const unsigned* __restrict__ bucketBase,
                                                   unsigned long long* __restrict__ pairs) {
    __shared__ unsigned cnt[NB];
    __shared__ unsigned lbase[NB + 1];
    __shared__ unsigned sbase[NB];
    __shared__ unsigned long long lp[CHUNK2];      // 32 KB staging
    int tid = threadIdx.x;
    cnt[tid] = 0;
    sbase[tid] = bucketBase[tid] + hist[(size_t)blockIdx.x * NB + tid];
    __syncthreads();

    unsigned bjs[EPT2], kls[EPT2], los[EPT2];
    int e0 = blockIdx.x * CHUNK2;
    // pass 1: bucket ids + local offsets
    #pragma unroll
    for (int k = 0; k < EPT2 / 4; ++k) {
        int idx = e0 + k * (BLOCK * 4) + tid * 4;
        if (idx + 4 <= n) {
            int4 v = *reinterpret_cast<const int4*>(x + idx);
            unsigned kk[4] = {(unsigned)v.x & TABLE_MASK, (unsigned)v.y & TABLE_MASK,
                              (unsigned)v.z & TABLE_MASK, (unsigned)v.w & TABLE_MASK};
            #pragma unroll
            for (int j = 0; j < 4; ++j) {
                int e = k * 4 + j;
                bjs[e] = kk[j] >> BSHIFT;
                kls[e] = kk[j] & KLOW_MASK;
                los[e] = atomicAdd(&cnt[bjs[e]], 1u);
            }
        } else {
            #pragma unroll
            for (int j = 0; j < 4; ++j) {
                int e = k * 4 + j;
                int i = idx + j;
                if (i < n) {
                    unsigned kv = (unsigned)x[i] & TABLE_MASK;
                    bjs[e] = kv >> BSHIFT;
                    kls[e] = kv & KLOW_MASK;
                    los[e] = atomicAdd(&cnt[bjs[e]], 1u);
                } else {
                    bjs[e] = BJ_INVALID;
                }
            }
        }
    }
    __syncthreads();
    // scan local counts -> local bucket bases
    {
        int v = (int)cnt[tid];
        int tot;
        int ex = blk_excl_scan<256>(v, tid, &tot);
        lbase[tid] = (unsigned)ex;
        if (tid == 255) lbase[256] = (unsigned)(ex + v);
    }
    __syncthreads();
    // pass 2: place pairs into LDS ordered by bucket
    #pragma unroll
    for (int k = 0; k < EPT2 / 4; ++k) {
        #pragma unroll
        for (int j = 0; j < 4; ++j) {
            int e = k * 4 + j;
            if (bjs[e] != BJ_INVALID) {
                unsigned pos = (unsigned)(e0 + k * (BLOCK * 4) + tid * 4 + j);
                lp[lbase[bjs[e]] + los[e]] =
                    ((unsigned long long)kls[e] << 32) | pos;
            }
        }
    }
    __syncthreads();
    // flush: wave per bucket, contiguous burst per bucket segment
    int wv = tid >> 6, ln = tid & 63;
    for (int j = wv; j < NB; j += BLOCK / 64) {
        unsigned ls = lbase[j], len = lbase[j + 1] - ls, gs = sbase[j];
        for (unsigned i = ln; i < len; i += 64)
            pairs[gs + i] = lp[ls + i];
    }
}

// ---------- D: per-bucket first-idx in LDS; coalesced table write + flag bytes ----------
__global__ __launch_bounds__(512) void k_bucket_min(const unsigned long long* __restrict__ pairs,
                                                    const unsigned* __restrict__ bucketBase,
                                                    int* __restrict__ table,
                                                    unsigned char* __restrict__ flag) {
    __shared__ int fi[KPB];                 // 32 KB
    int j = blockIdx.x, tid = threadIdx.x;
    for (int k = tid; k < KPB; k += 512) fi[k] = INF_PAT;
    __syncthreads();
    unsigned s = bucketBase[j], e = bucketBase[j + 1];
    for (unsigned idx = s + tid; idx < e; idx += 512) {
        unsigned long long p = pairs[idx];
        atomicMin(&fi[(unsigned)(p >> 32)], (int)(unsigned)p);
    }
    __syncthreads();
    int* dst = table + (size_t)j * KPB;
    for (int k = tid; k < KPB; k += 512) dst[k] = fi[k];
    // flag bytes: every position written exactly once (one pair per element)
    for (unsigned idx = s + tid; idx < e; idx += 512) {
        unsigned long long p = pairs[idx];     // L2-hot re-read
        unsigned pos = (unsigned)p;
        flag[pos] = (unsigned char)(fi[(unsigned)(p >> 32)] == (int)pos);
    }
}

// ---------- E: sequential flag bytes -> bitmask + blockSums ----------
__global__ __launch_bounds__(BLOCK) void k_flags(const unsigned char* __restrict__ flag, int n,
                                                 int* __restrict__ blockSums,
                                                 unsigned long long* __restrict__ bitmask) {
    int tid = threadIdx.x;
    int lane = tid & 63, w = tid >> 6;
    int base = blockIdx.x * CHUNK + tid * EPT;
    int flags[EPT];
    if (base + EPT <= n) {
        uchar4 f = *reinterpret_cast<const uchar4*>(flag + base);
        flags[0] = f.x; flags[1] = f.y; flags[2] = f.z; flags[3] = f.w;
    } else {
        #pragma unroll
        for (int j = 0; j < EPT; ++j)
            flags[j] = (base + j < n) ? flag[base + j] : 0;
    }
    int cnt = 0;
    #pragma unroll
    for (int j = 0; j < EPT; ++j) {
        unsigned long long mj = __ballot(flags[j]);
        if (lane == 0) bitmask[((size_t)blockIdx.x * (BLOCK / 64) + w) * EPT + j] = mj;
        cnt += flags[j];
    }
    for (int off = 32; off > 0; off >>= 1)
        cnt += __shfl_down(cnt, off, 64);
    __shared__ int ws[BLOCK / 64];
    if (lane == 0) ws[w] = cnt;
    __syncthreads();
    if (tid == 0) {
        int s = 0;
        #pragma unroll
        for (int q = 0; q < BLOCK / 64; ++q) s += ws[q];
        blockSums[blockIdx.x] = s;
    }
}

// ---------- K3: single-block scan of blockSums ----------
__global__ __launch_bounds__(1024) void k_scan(int* __restrict__ sums, int B) {
    int tid = threadIdx.x;
    int carry = 0;
    for (int b0 = 0; b0 < B; b0 += 1024) {
        int b = b0 + tid;
        int v = (b < B) ? sums[b] : 0;
        int tot;
        int excl = blk_excl_scan<1024>(v, tid, &tot);
        if (b < B) sums[b] = carry + excl;
        carry += tot;
    }
}

// ---------- K4: assign ranks using the bitmask ----------
__global__ __launch_bounds__(BLOCK) void k_rank(const int* __restrict__ x, int n,
                                                int* __restrict__ table,
                                                const int* __restrict__ blockSums,
                                                const unsigned long long* __restrict__ bitmask) {
    int tid = threadIdx.x;
    int lane = tid & 63, w = tid >> 6;
    int base = blockIdx.x * CHUNK + tid * EPT;
    const unsigned long long* bm = bitmask + ((size_t)blockIdx.x * (BLOCK / 64) + w) * EPT;
    int flags[EPT];
    int cnt = 0;
    #pragma unroll
    for (int j = 0; j < EPT; ++j) {
        flags[j] = (int)((bm[j] >> lane) & 1ull);
        cnt += flags[j];
    }
    __shared__ int lds[BLOCK];
    lds[tid] = cnt;
    __syncthreads();
    for (int off = 1; off < BLOCK; off <<= 1) {
        int t = (tid >= off) ? lds[tid - off] : 0;
        __syncthreads();
        lds[tid] += t;
        __syncthreads();
    }
    int r = blockSums[blockIdx.x] + lds[tid] - cnt;
    if (cnt) {
        if (base + EPT <= n) {
            int4 v = *reinterpret_cast<const int4*>(x + base);
            if (flags[0]) table[(unsigned)v.x & TABLE_MASK] = (r++) | RANK_BIT;
            if (flags[1]) table[(unsigned)v.y & TABLE_MASK] = (r++) | RANK_BIT;
            if (flags[2]) table[(unsigned)v.z & TABLE_MASK] = (r++) | RANK_BIT;
            if (flags[3]) table[(unsigned)v.w & TABLE_MASK] = (r++) | RANK_BIT;
        } else {
            #pragma unroll
            for (int j = 0; j < EPT; ++j)
                if (flags[j]) table[(unsigned)x[base + j] & TABLE_MASK] = (r++) | RANK_BIT;
        }
    }
}

// ---------- K5: gather rank, apply max_tokens cutoff ----------
__global__ __launch_bounds__(BLOCK) void k_out(const int* __restrict__ x, int n,
                                               const int* __restrict__ table,
                                               const int* __restrict__ mtp,
                                               int* __restrict__ out) {
    int mt = mtp[0];
    int base = (blockIdx.x * BLOCK + threadIdx.x) * EPT;
    if (base + EPT <= n) {
        int4 v = *reinterpret_cast<const int4*>(x + base);
        int4 o;
        int r;
        r = table[(unsigned)v.x & TABLE_MASK] & RANK_MASK; o.x = (r < mt) ? r + 1 : 0;
        r = table[(unsigned)v.y & TABLE_MASK] & RANK_MASK; o.y = (r < mt) ? r + 1 : 0;
        r = table[(unsigned)v.z & TABLE_MASK] & RANK_MASK; o.z = (r < mt) ? r + 1 : 0;
        r = table[(unsigned)v.w & TABLE_MASK] & RANK_MASK; o.w = (r < mt) ? r + 1 : 0;
        *reinterpret_cast<int4*>(out + base) = o;
    } else {
        for (int i = base; i < n; ++i) {
            int r = table[(unsigned)x[i] & TABLE_MASK] & RANK_MASK;
            out[i] = (r < mt) ? r + 1 : 0;
        }
    }
}

// ---------- fallbacks (small ws): device-scope atomics + gather count ----------
__global__ __launch_bounds__(BLOCK) void k_first_idx(const int* __restrict__ x, int n,
                                                     int* __restrict__ table) {
    int base = (blockIdx.x * BLOCK + threadIdx.x) * EPT;
    for (int i = base; i < min(base + EPT, n); ++i)
        atomicMin(&table[(unsigned)x[i] & TABLE_MASK], i);
}
__global__ __launch_bounds__(BLOCK) void k_count(const int* __restrict__ x, int n,
                                                 const int* __restrict__ table,
                                                 int* __restrict__ blockSums,
                                                 unsigned long long* __restrict__ bitmask) {
    int tid = threadIdx.x;
    int lane = tid & 63, w = tid >> 6;
    int base = blockIdx.x * CHUNK + tid * EPT;
    int flags[EPT];
    #pragma unroll
    for (int j = 0; j < EPT; ++j) {
        flags[j] = 0;
        if (base + j < n)
            flags[j] = (table[(unsigned)x[base + j] & TABLE_MASK] == base + j);
    }
    int cnt = 0;
    #pragma unroll
    for (int j = 0; j < EPT; ++j) {
        unsigned long long mj = __ballot(flags[j]);
        if (lane == 0) bitmask[((size_t)blockIdx.x * (BLOCK / 64) + w) * EPT + j] = mj;
        cnt += flags[j];
    }
    for (int off = 32; off > 0; off >>= 1)
        cnt += __shfl_down(cnt, off, 64);
    __shared__ int ws[BLOCK / 64];
    if (lane == 0) ws[w] = cnt;
    __syncthreads();
    if (tid == 0) {
        int s = 0;
        #pragma unroll
        for (int q = 0; q < BLOCK / 64; ++q) s += ws[q];
        blockSums[blockIdx.x] = s;
    }
}

extern "C" void kernel_launch(void* const* d_in, const int* in_sizes, int n_in,
                              void* d_out, int out_size, void* d_ws, size_t ws_size,
                              hipStream_t stream) {
    const int* x   = (const int*)d_in[0];
    const int* mtp = (const int*)d_in[1];
    int n = in_sizes[0];
    int* out = (int*)d_out;

    int SB  = (n + CHUNK  - 1) / CHUNK;    // 1024-granularity blocks
    int SB2 = (n + CHUNK2 - 1) / CHUNK2;   // 4096-granularity blocks

    auto align16 = [](size_t v) { return (v + 15) & ~(size_t)15; };
    size_t off = 0;
    int* table = (int*)d_ws;                                    off = align16(off + (size_t)TABLE_SIZE * 4);
    unsigned long long* pairs = (unsigned long long*)((char*)d_ws + off); off = align16(off + (size_t)n * 8);
    unsigned char* flag = (unsigned char*)((char*)d_ws + off);  off = align16(off + (size_t)n);
    unsigned* hist = (unsigned*)((char*)d_ws + off);            off = align16(off + (size_t)SB2 * NB * 4);
    unsigned* bucketTot = (unsigned*)((char*)d_ws + off);       off = align16(off + (size_t)NB * 4);
    unsigned* bucketBase = (unsigned*)((char*)d_ws + off);      off = align16(off + (size_t)(NB + 1) * 4);
    int* blockSums = (int*)((char*)d_ws + off);                 off = align16(off + (size_t)SB * 4);
    unsigned long long* bitmask = (unsigned long long*)((char*)d_ws + off);
    off = align16(off + (size_t)SB * (BLOCK / 64) * EPT * 8);

    if (ws_size >= off) {
        k_hist      <<<SB2, BLOCK, 0, stream>>>(x, n, hist);
        k_colscan   <<<NB,  256,   0, stream>>>(hist, SB2, bucketTot);
        k_bucketbase<<<1,   256,   0, stream>>>(bucketTot, bucketBase);
        k_scatter   <<<SB2, BLOCK, 0, stream>>>(x, n, hist, bucketBase, pairs);
        k_bucket_min<<<NB,  512,   0, stream>>>(pairs, bucketBase, table, flag);
        k_flags     <<<SB,  BLOCK, 0, stream>>>(flag, n, blockSums, bitmask);
    } else {
        hipMemsetAsync(table, 0x7F, (size_t)TABLE_SIZE * 4, stream);
        k_first_idx<<<SB, BLOCK, 0, stream>>>(x, n, table);
        k_count    <<<SB, BLOCK, 0, stream>>>(x, n, table, blockSums, bitmask);
    }
    k_scan <<<1, 1024, 0, stream>>>(blockSums, SB);
    k_rank <<<SB, BLOCK, 0, stream>>>(x, n, table, blockSums, bitmask);
    k_out  <<<SB, BLOCK, 0, stream>>>(x, n, table, mtp, out);
}